// Round 2
// baseline (415.052 us; speedup 1.0000x reference)
//
#include <hip/hip_runtime.h>

// LoRAConnector: B=4, T=2048, N=4, C=1024, A=8, nC=4096, SINKHORN_ITERS=20
//
// Round 2 design: kill the VMEM line-transaction bottleneck.
//  - 512 blocks x 512 threads; block = 16 consecutive tokens (one adapter).
//  - thread -> (g = tid&15: token, l = tid>>4: 0..31 d4-slice).
//    Per wave only 4 distinct phi addresses (consecutive float4s) -> each
//    phi load instr = <=4 adjacent 64B lines instead of 16 scattered ones.
//    Total phi line traffic drops ~16x vs round 1.
//  - No xs[] register cache: epilogue re-reads x (L2/L3-warm, per-block
//    working set 64 KB just touched). Frees 64 VGPRs for load pipelining.
//  - out[i,c] = sum_j (M[i,j] + H_post[i]*H_pre[j]) * x[j,c] as before.
//  - sinkhorn: 256 threads, thread = (token tau = tid>>4, elem sig = tid&15);
//    row sums shfl_xor 1,2; col sums shfl_xor 4,8.

#define NC4 1024       // nC/4 float4s per token
#define GTOK 16        // tokens per block

__global__ __launch_bounds__(512, 4) void lora_connector_kernel(
    const float* __restrict__ x,
    const float* __restrict__ inw,
    const float* __restrict__ phi_pre,
    const float* __restrict__ phi_post,
    const float* __restrict__ phi_res,
    const float* __restrict__ b_pre,
    const float* __restrict__ b_post,
    const float* __restrict__ b_res,
    const float* __restrict__ alpha_pre,
    const float* __restrict__ alpha_post,
    const float* __restrict__ alpha_res,
    const int*   __restrict__ adapter_indices,
    float* __restrict__ out)
{
    const int tid = threadIdx.x;
    const int g   = tid & 15;        // token within block
    const int l   = tid >> 4;        // d4-slice 0..31
    const int tok = blockIdx.x * GTOK + g;
    const int idx = adapter_indices[blockIdx.x >> 7];   // 128 blocks per batch

    const float4* __restrict__ x4p = (const float4*)x + (size_t)tok * NC4;
    const float4* __restrict__ w4p = (const float4*)inw + (size_t)idx * NC4;
    const float4* __restrict__ pp4 = (const float4*)phi_pre  + (size_t)idx * 4096;
    const float4* __restrict__ po4 = (const float4*)phi_post + (size_t)idx * 4096;
    const float4* __restrict__ pr4 = (const float4*)phi_res  + (size_t)idx * 16384;

    float acc[25];
    #pragma unroll
    for (int j = 0; j < 25; ++j) acc[j] = 0.0f;

    // ---- Phase 1: stream x,w,phi; accumulate sumsq + 24 dots of (w*x).phi ----
    #pragma unroll 4
    for (int m = 0; m < 32; ++m) {
        const int d4 = m * 32 + l;
        const float4 xv = x4p[d4];
        const float4 wv = w4p[d4];
        acc[24] = fmaf(xv.x, xv.x, fmaf(xv.y, xv.y, fmaf(xv.z, xv.z, fmaf(xv.w, xv.w, acc[24]))));
        const float xw[4] = { xv.x * wv.x, xv.y * wv.y, xv.z * wv.z, xv.w * wv.w };
        #pragma unroll
        for (int e = 0; e < 4; ++e) {
            const int d = d4 * 4 + e;
            const float s = xw[e];
            const float4 a = pp4[d];
            acc[0] = fmaf(s, a.x, acc[0]);
            acc[1] = fmaf(s, a.y, acc[1]);
            acc[2] = fmaf(s, a.z, acc[2]);
            acc[3] = fmaf(s, a.w, acc[3]);
            const float4 p = po4[d];
            acc[4] = fmaf(s, p.x, acc[4]);
            acc[5] = fmaf(s, p.y, acc[5]);
            acc[6] = fmaf(s, p.z, acc[6]);
            acc[7] = fmaf(s, p.w, acc[7]);
            #pragma unroll
            for (int q = 0; q < 4; ++q) {
                const float4 r = pr4[d * 4 + q];
                acc[8 + q * 4 + 0] = fmaf(s, r.x, acc[8 + q * 4 + 0]);
                acc[8 + q * 4 + 1] = fmaf(s, r.y, acc[8 + q * 4 + 1]);
                acc[8 + q * 4 + 2] = fmaf(s, r.z, acc[8 + q * 4 + 2]);
                acc[8 + q * 4 + 3] = fmaf(s, r.w, acc[8 + q * 4 + 3]);
            }
        }
    }

    // ---- Phase 2a: reduce over the wave's 4 l-slices (lane bits 4,5) ----
    #pragma unroll
    for (int j = 0; j < 25; ++j) {
        float v = acc[j];
        v += __shfl_xor(v, 16);
        v += __shfl_xor(v, 32);
        acc[j] = v;
    }

    // ---- Phase 2b: cross-wave partials to LDS ----
    __shared__ float red[8][16][26];
    __shared__ float Wl[16][17];
    const int wv = tid >> 6;
    const int lw = tid & 63;
    if (lw < 16) {
        #pragma unroll
        for (int j = 0; j < 25; ++j) red[wv][lw][j] = acc[j];
    }
    __syncthreads();

    // ---- Phase 2c: gates + sinkhorn; threads 0..255 = (token tau, elem sig) ----
    if (tid < 256) {
        const int tau = tid >> 4;
        const int sig = tid & 15;
        const int si  = sig >> 2;
        const int sj  = sig & 3;
        float t_res = 0.f, t_ss = 0.f, t_pre = 0.f, t_post = 0.f;
        #pragma unroll
        for (int w = 0; w < 8; ++w) {
            t_res  += red[w][tau][8 + sig];
            t_ss   += red[w][tau][24];
            t_pre  += red[w][tau][sj];
            t_post += red[w][tau][4 + si];
        }
        const float inv_rms = rsqrtf(t_ss * (1.0f / 4096.0f) + 1e-5f);
        const float zp = fmaf(alpha_pre[idx],  t_pre  * inv_rms, b_pre[idx * 4 + sj]);
        const float Hpre = 1.0f / (1.0f + __expf(-zp));
        const float zq = fmaf(alpha_post[idx], t_post * inv_rms, b_post[idx * 4 + si]);
        const float Hpost = 2.0f / (1.0f + __expf(-zq));

        float Mv = __expf(fmaf(alpha_res[idx], t_res * inv_rms, b_res[idx * 16 + sig]));
        #pragma unroll
        for (int it = 0; it < 20; ++it) {
            float rs = Mv + __shfl_xor(Mv, 1);   // sum over sj (lane bits 0,1)
            rs += __shfl_xor(rs, 2);
            Mv *= __builtin_amdgcn_rcpf(rs);
            float cs = Mv + __shfl_xor(Mv, 4);   // sum over si (lane bits 2,3)
            cs += __shfl_xor(cs, 8);
            Mv *= __builtin_amdgcn_rcpf(cs);
        }
        Wl[tau][sig] = fmaf(Hpost, Hpre, Mv);
    }
    __syncthreads();

    // ---- Phase 3: out[i,c] = sum_j W[i][j]*x[j,c]; x re-read (cache-warm) ----
    float W[4][4];
    #pragma unroll
    for (int ss = 0; ss < 16; ++ss) W[ss >> 2][ss & 3] = Wl[g][ss];

    float4* __restrict__ out4 = (float4*)out + (size_t)tok * NC4;
    #pragma unroll 2
    for (int k = 0; k < 8; ++k) {
        const int c4 = k * 32 + l;
        const float4 x0 = x4p[c4];
        const float4 x1 = x4p[256 + c4];
        const float4 x2 = x4p[512 + c4];
        const float4 x3 = x4p[768 + c4];
        #pragma unroll
        for (int i = 0; i < 4; ++i) {
            float4 o;
            o.x = fmaf(W[i][0], x0.x, fmaf(W[i][1], x1.x, fmaf(W[i][2], x2.x, W[i][3] * x3.x)));
            o.y = fmaf(W[i][0], x0.y, fmaf(W[i][1], x1.y, fmaf(W[i][2], x2.y, W[i][3] * x3.y)));
            o.z = fmaf(W[i][0], x0.z, fmaf(W[i][1], x1.z, fmaf(W[i][2], x2.z, W[i][3] * x3.z)));
            o.w = fmaf(W[i][0], x0.w, fmaf(W[i][1], x1.w, fmaf(W[i][2], x2.w, W[i][3] * x3.w)));
            out4[i * 256 + c4] = o;
        }
    }
}

extern "C" void kernel_launch(void* const* d_in, const int* in_sizes, int n_in,
                              void* d_out, int out_size, void* d_ws, size_t ws_size,
                              hipStream_t stream) {
    const float* x         = (const float*)d_in[0];
    const float* inw       = (const float*)d_in[1];
    const float* phi_pre   = (const float*)d_in[2];
    const float* phi_post  = (const float*)d_in[3];
    const float* phi_res   = (const float*)d_in[4];
    const float* b_pre     = (const float*)d_in[5];
    const float* b_post    = (const float*)d_in[6];
    const float* b_res     = (const float*)d_in[7];
    const float* alpha_pre = (const float*)d_in[8];
    const float* alpha_post= (const float*)d_in[9];
    const float* alpha_res = (const float*)d_in[10];
    const int*   adapter   = (const int*)d_in[11];
    float* out = (float*)d_out;

    dim3 grid(8192 / GTOK);   // 512 blocks, 16 tokens each
    dim3 block(512);
    lora_connector_kernel<<<grid, block, 0, stream>>>(
        x, inw, phi_pre, phi_post, phi_res,
        b_pre, b_post, b_res,
        alpha_pre, alpha_post, alpha_res,
        adapter, out);
}

// Round 3
// 412.394 us; speedup vs baseline: 1.0064x; 1.0064x over previous
//
#include <hip/hip_runtime.h>

// LoRAConnector: B=4, T=2048, N=4, C=1024, A=8, nC=4096, SINKHORN_ITERS=20
//
// Round 3: LDS-transposed phi, wave=token, everything-coalesced.
//  - 2048 blocks x 256 threads; block = 4 tokens; wave w = token w; lane l.
//  - x in regs: xs[16] float4 at d4 = m*64+l (1 KB/instr coalesced loads,
//    read exactly once; reused by the epilogue in-register).
//  - phi staged per 256-d chunk into LDS TRANSPOSED: s_pp[n][d_local] etc.
//    Staging global loads are 1 KB/instr coalesced; compute-side reads are
//    ds_read_b128 of [n][4l..4l+3] -> lane coeff 4 in word addr -> 8 words
//    per bank = pure BW floor, no conflicts. s_pr gets a 1-bit XOR column
//    swizzle so the transposing scalar stores are 2-way (free) not 4-way.
//  - sinkhorn fully per-wave (lane sig = l&15, shfl_xor 1,2 rows / 4,8 cols),
//    no cross-wave reduction, no epilogue barrier.
//  - out[i,c] = sum_j (M[i,j]+Hpost[i]*Hpre[j]) * x[j,c], stores 1 KB/instr.

#define NC4 1024        // float4s per token

__global__ __launch_bounds__(256, 3) void lora_connector_kernel(
    const float* __restrict__ x,
    const float* __restrict__ inw,
    const float* __restrict__ phi_pre,
    const float* __restrict__ phi_post,
    const float* __restrict__ phi_res,
    const float* __restrict__ b_pre,
    const float* __restrict__ b_post,
    const float* __restrict__ b_res,
    const float* __restrict__ alpha_pre,
    const float* __restrict__ alpha_post,
    const float* __restrict__ alpha_res,
    const int*   __restrict__ adapter_indices,
    float* __restrict__ out)
{
    const int tid = threadIdx.x;
    const int l   = tid & 63;          // lane
    const int wv  = tid >> 6;          // wave index = token within block
    const int tok = blockIdx.x * 4 + wv;
    const int idx = adapter_indices[blockIdx.x >> 9];   // 512 blocks per batch

    __shared__ float s_pp[4][256];
    __shared__ float s_po[4][256];
    __shared__ float s_pr[16][256];

    const float4* __restrict__ x4p = (const float4*)x + (size_t)tok * NC4;
    const float4* __restrict__ w4p = (const float4*)inw + (size_t)idx * NC4;
    const float4* __restrict__ pp4 = (const float4*)phi_pre  + (size_t)idx * 4096;
    const float4* __restrict__ po4 = (const float4*)phi_post + (size_t)idx * 4096;
    const float4* __restrict__ pr4 = (const float4*)phi_res  + (size_t)idx * 16384;

    // ---- load x once; sumsq on the fly ----
    float4 xs[16];
    float acc[25];
    #pragma unroll
    for (int j = 0; j < 25; ++j) acc[j] = 0.0f;
    #pragma unroll
    for (int m = 0; m < 16; ++m) {
        const float4 xv = x4p[m * 64 + l];
        xs[m] = xv;
        acc[24] = fmaf(xv.x, xv.x, fmaf(xv.y, xv.y, fmaf(xv.z, xv.z, fmaf(xv.w, xv.w, acc[24]))));
    }

    // ---- 16 chunks of 256 d; stage phi transposed, accumulate 24 dots ----
    #pragma unroll
    for (int m = 0; m < 16; ++m) {
        if (m) __syncthreads();
        {   // stage: coalesced global -> transposed LDS
            const float4 a = pp4[m * 256 + tid];
            s_pp[0][tid] = a.x; s_pp[1][tid] = a.y; s_pp[2][tid] = a.z; s_pp[3][tid] = a.w;
            const float4 p = po4[m * 256 + tid];
            s_po[0][tid] = p.x; s_po[1][tid] = p.y; s_po[2][tid] = p.z; s_po[3][tid] = p.w;
            #pragma unroll
            for (int k = 0; k < 4; ++k) {
                const int j  = k * 256 + tid;
                const float4 r = pr4[m * 1024 + j];
                const int dl = j >> 2;
                const int q  = j & 3;
                const int col = dl ^ ((q & 1) << 4);   // 1-bit swizzle: 2-way stores (free)
                s_pr[4 * q + 0][col] = r.x;
                s_pr[4 * q + 1][col] = r.y;
                s_pr[4 * q + 2][col] = r.z;
                s_pr[4 * q + 3][col] = r.w;
            }
        }
        __syncthreads();
        // compute: this chunk covers exactly xs[m]
        const float4 xv = xs[m];
        const float4 wg = w4p[m * 64 + l];
        const float4 xw = { xv.x * wg.x, xv.y * wg.y, xv.z * wg.z, xv.w * wg.w };
        #pragma unroll
        for (int n = 0; n < 4; ++n) {
            const float4 a = ((const float4*)s_pp[n])[l];
            acc[n]     = fmaf(xw.x, a.x, fmaf(xw.y, a.y, fmaf(xw.z, a.z, fmaf(xw.w, a.w, acc[n]))));
            const float4 p = ((const float4*)s_po[n])[l];
            acc[4 + n] = fmaf(xw.x, p.x, fmaf(xw.y, p.y, fmaf(xw.z, p.z, fmaf(xw.w, p.w, acc[4 + n]))));
        }
        #pragma unroll
        for (int n = 0; n < 16; ++n) {
            const int col4 = l ^ (((n >> 2) & 1) << 2);  // matches store swizzle
            const float4 r = ((const float4*)s_pr[n])[col4];
            acc[8 + n] = fmaf(xw.x, r.x, fmaf(xw.y, r.y, fmaf(xw.z, r.z, fmaf(xw.w, r.w, acc[8 + n]))));
        }
    }

    // ---- per-wave full butterfly: every lane gets all 25 totals ----
    #pragma unroll
    for (int j = 0; j < 25; ++j) {
        float v = acc[j];
        v += __shfl_xor(v, 1);
        v += __shfl_xor(v, 2);
        v += __shfl_xor(v, 4);
        v += __shfl_xor(v, 8);
        v += __shfl_xor(v, 16);
        v += __shfl_xor(v, 32);
        acc[j] = v;
    }

    // ---- gates + sinkhorn (per-wave; lanes 16..63 mirror 0..15) ----
    const float inv_rms = rsqrtf(acc[24] * (1.0f / 4096.0f) + 1e-5f);
    const float apre  = alpha_pre[idx];
    const float apost = alpha_post[idx];
    const float ares  = alpha_res[idx];
    float Hpre[4], Hpost[4];
    #pragma unroll
    for (int n = 0; n < 4; ++n) {
        const float zp = fmaf(apre,  acc[n]     * inv_rms, b_pre[idx * 4 + n]);
        Hpre[n]  = 1.0f / (1.0f + __expf(-zp));
        const float zq = fmaf(apost, acc[4 + n] * inv_rms, b_post[idx * 4 + n]);
        Hpost[n] = 2.0f / (1.0f + __expf(-zq));
    }

    const int sig = l & 15;
    float Mv = __expf(fmaf(ares, acc[8 + sig] * inv_rms, b_res[idx * 16 + sig]));
    #pragma unroll
    for (int it = 0; it < 20; ++it) {
        float rs = Mv + __shfl_xor(Mv, 1);   // sum over columns j (bits 0,1)
        rs += __shfl_xor(rs, 2);
        Mv *= __builtin_amdgcn_rcpf(rs);
        float cs = Mv + __shfl_xor(Mv, 4);   // sum over rows i (bits 2,3)
        cs += __shfl_xor(cs, 8);
        Mv *= __builtin_amdgcn_rcpf(cs);
    }

    float W[4][4];
    #pragma unroll
    for (int ss = 0; ss < 16; ++ss)
        W[ss >> 2][ss & 3] = fmaf(Hpost[ss >> 2], Hpre[ss & 3], __shfl(Mv, ss));

    // ---- epilogue: out from registers, 1 KB/instr coalesced stores ----
    float4* __restrict__ out4 = (float4*)out + (size_t)tok * NC4;
    #pragma unroll
    for (int k = 0; k < 4; ++k) {
        const float4 x0 = xs[0 * 4 + k];
        const float4 x1 = xs[1 * 4 + k];
        const float4 x2 = xs[2 * 4 + k];
        const float4 x3 = xs[3 * 4 + k];
        #pragma unroll
        for (int i = 0; i < 4; ++i) {
            float4 o;
            o.x = fmaf(W[i][0], x0.x, fmaf(W[i][1], x1.x, fmaf(W[i][2], x2.x, W[i][3] * x3.x)));
            o.y = fmaf(W[i][0], x0.y, fmaf(W[i][1], x1.y, fmaf(W[i][2], x2.y, W[i][3] * x3.y)));
            o.z = fmaf(W[i][0], x0.z, fmaf(W[i][1], x1.z, fmaf(W[i][2], x2.z, W[i][3] * x3.z)));
            o.w = fmaf(W[i][0], x0.w, fmaf(W[i][1], x1.w, fmaf(W[i][2], x2.w, W[i][3] * x3.w)));
            out4[i * 256 + k * 64 + l] = o;
        }
    }
}

extern "C" void kernel_launch(void* const* d_in, const int* in_sizes, int n_in,
                              void* d_out, int out_size, void* d_ws, size_t ws_size,
                              hipStream_t stream) {
    const float* x         = (const float*)d_in[0];
    const float* inw       = (const float*)d_in[1];
    const float* phi_pre   = (const float*)d_in[2];
    const float* phi_post  = (const float*)d_in[3];
    const float* phi_res   = (const float*)d_in[4];
    const float* b_pre     = (const float*)d_in[5];
    const float* b_post    = (const float*)d_in[6];
    const float* b_res     = (const float*)d_in[7];
    const float* alpha_pre = (const float*)d_in[8];
    const float* alpha_post= (const float*)d_in[9];
    const float* alpha_res = (const float*)d_in[10];
    const int*   adapter   = (const int*)d_in[11];
    float* out = (float*)d_out;

    dim3 grid(2048);    // 4 tokens per block
    dim3 block(256);
    lora_connector_kernel<<<grid, block, 0, stream>>>(
        x, inw, phi_pre, phi_post, phi_res,
        b_pre, b_post, b_res,
        alpha_pre, alpha_post, alpha_res,
        adapter, out);
}